// Round 5
// baseline (335.643 us; speedup 1.0000x reference)
//
#include <hip/hip_runtime.h>
#include <hip/hip_bf16.h>
#include <stdint.h>
#include <cstddef>

// Problem constants
#define BB  2
#define CC  512
#define TT  32
#define HWP 196   // H*W = 14*14
#define NH  8
#define KWIN 9
#define CID 64    // C / N
#define PPAD 4    // (K-1)/2
#define TP  40    // T + 2P
#define MTOT 12544  // BB*TT*HWP
#define NTOT 1536   // 3*CC (Q|K|V output channels)
#define VSLOT 224   // padded per-frame key slots (7*32)
#define LOG2E 1.44269504f

typedef unsigned short u16;
typedef unsigned int   u32;
typedef __attribute__((ext_vector_type(8))) short short8;
typedef __attribute__((ext_vector_type(4))) float floatx4;

__device__ __forceinline__ u16 f2bf(float f) {
    u32 u = __float_as_uint(f);
    u32 r = (u + 0x7fffu + ((u >> 16) & 1u)) >> 16;
    return (u16)r;
}
__device__ __forceinline__ u32 pack2bf(float a, float b) {
    return (u32)f2bf(a) | ((u32)f2bf(b) << 16);
}
// Truncating pack: [hi16(b) : hi16(a)] in one v_perm_b32.
__device__ __forceinline__ u32 packtrunc(float a, float b) {
    return __builtin_amdgcn_perm(__float_as_uint(b), __float_as_uint(a), 0x07060302u);
}

// ---------------------------------------------------------------------------
// Prep 1: W concat + fp32->bf16.  Wbf[oc][c], oc = kind*512 + n*64 + ci.
// ---------------------------------------------------------------------------
__global__ __launch_bounds__(256) void convert_w(
    const float* __restrict__ Wq, const float* __restrict__ Wk,
    const float* __restrict__ Wv, u16* __restrict__ Wbf)
{
    int id = blockIdx.x * 256 + threadIdx.x;      // one u32 (2 elems) each
    if (id >= NTOT * CC / 2) return;
    int c2 = id & 255;
    int oc = id >> 8;
    int kind = oc >> 9;
    int idx = oc & 511;
    const float* src = (kind == 0 ? Wq : (kind == 1 ? Wk : Wv)) + (size_t)idx * CC + c2 * 2;
    ((u32*)Wbf)[id] = pack2bf(src[0], src[1]);
}

// ---------------------------------------------------------------------------
// Prep 2: transpose x[b][c][t][p] fp32 -> xt[(b*T+t)*HW+p][c] bf16.
// xt lives in d_out (dead until attn overwrites with z).
// ---------------------------------------------------------------------------
__global__ __launch_bounds__(256) void transpose_x(
    const float* __restrict__ x, u16* __restrict__ xt)
{
    __shared__ float T[64 * 197];
    int bx = blockIdx.x;
    int ct = bx & 7; bx >>= 3;
    int t = bx & 31;
    int b = bx >> 5;
    int tid = threadIdx.x;
    const float* src = x + ((size_t)(b * CC + ct * 64) * TT + t) * HWP;
    for (int i = tid; i < 64 * HWP; i += 256) {
        int c = i / HWP;
        int p = i - c * HWP;
        T[c * 197 + p] = src[(size_t)c * (TT * HWP) + p];
    }
    __syncthreads();
    u16* dst = xt + (size_t)((b * TT + t) * HWP) * CC + ct * 64;
    for (int i = tid; i < HWP * 64; i += 256) {
        int p = i >> 6;
        int c = i & 63;
        dst[(size_t)p * CC + c] = f2bf(T[c * 197 + p]);
    }
}

// ---------------------------------------------------------------------------
// Prep 3: fill pad frames (tp in {0..3, 36..39}): K rows and Vtp rows = bias.
// ---------------------------------------------------------------------------
__global__ __launch_bounds__(256) void pad_fill(
    const float* __restrict__ bk, const float* __restrict__ bv,
    u16* __restrict__ Kout, u16* __restrict__ Vtp)
{
    int id = blockIdx.x * 256 + threadIdx.x;
    const int kper = 2 * NH * 8 * HWP * 32;        // 802816 u32 (K)
    const int vper = 2 * NH * 8 * 64 * (VSLOT/2);  // 917504 u32 (Vtp)
    if (id >= kper + vper) return;
    if (id < kper) {
        int i = id;
        int ci2 = i & 31; i >>= 5;
        int p = i % HWP;  i /= HWP;
        int fr = i & 7;   i >>= 3;
        int head = i & 7;
        int b = i >> 3;
        int tp = fr < 4 ? fr : fr + 32;
        const float* bias = bk + head * CID + ci2 * 2;
        size_t addr = (((size_t)(b * NH + head) * TP + tp) * HWP + p) * 32 + ci2;
        ((u32*)Kout)[addr] = pack2bf(bias[0], bias[1]);
    } else {
        int i = id - kper;
        int s2 = i % (VSLOT/2); i /= (VSLOT/2);
        int ci = i & 63; i >>= 6;
        int fr = i & 7;  i >>= 3;
        int head = i & 7;
        int b = i >> 3;
        int tp = fr < 4 ? fr : fr + 32;
        float bias = bv[head * CID + ci];
        size_t addr = (((size_t)(b * NH + head) * TP + tp) * 64 + ci) * (VSLOT/2) + s2;
        ((u32*)Vtp)[addr] = pack2bf(bias, bias);   // whole row = bias[ci]
    }
}

// ---------------------------------------------------------------------------
// MFMA projection GEMM: Out^T[m=(b,t,p), n=oc] = xt[m,c] . Wbf[n,c] + bias[n].
// Epilogue: Q scaled by log2(e) (softmax exp2 trick); K rows [p][ci];
// V transposed+permuted per frame: Vtp[slab][tp][ci][slot(p)].
// ---------------------------------------------------------------------------
__global__ __launch_bounds__(256) void proj_gemm(
    const u16* __restrict__ xt, const u16* __restrict__ Wbf,
    const float* __restrict__ bq, const float* __restrict__ bk,
    const float* __restrict__ bv,
    u16* __restrict__ Qout, u16* __restrict__ Kout, u16* __restrict__ Vtp)
{
    int bx = blockIdx.x;
    int nb = bx % 6;
    int mt = bx / 6;
    int tid = threadIdx.x;
    int wave = tid >> 6, lane = tid & 63, quad = lane >> 4, l15 = lane & 15;
    int mbase = mt * 64;
    int nbase = nb * 256 + wave * 64;

    floatx4 acc[4][4];
    #pragma unroll
    for (int ms = 0; ms < 4; ms++)
        #pragma unroll
        for (int ns = 0; ns < 4; ns++)
            acc[ms][ns] = (floatx4){0.f, 0.f, 0.f, 0.f};

    const u16* ap[4];
    const u16* bp[4];
    #pragma unroll
    for (int ms = 0; ms < 4; ms++)
        ap[ms] = xt + (size_t)(mbase + ms * 16 + l15) * CC + quad * 8;
    #pragma unroll
    for (int ns = 0; ns < 4; ns++)
        bp[ns] = Wbf + (size_t)(nbase + ns * 16 + l15) * CC + quad * 8;

    #pragma unroll 2
    for (int kc = 0; kc < 16; kc++) {
        short8 af[4], bf[4];
        #pragma unroll
        for (int ms = 0; ms < 4; ms++) af[ms] = *(const short8*)(ap[ms] + kc * 32);
        #pragma unroll
        for (int ns = 0; ns < 4; ns++) bf[ns] = *(const short8*)(bp[ns] + kc * 32);
        #pragma unroll
        for (int ms = 0; ms < 4; ms++)
            #pragma unroll
            for (int ns = 0; ns < 4; ns++)
                acc[ms][ns] = __builtin_amdgcn_mfma_f32_16x16x32_bf16(
                    af[ms], bf[ns], acc[ms][ns], 0, 0, 0);
    }

    float biasv[4];
    #pragma unroll
    for (int ns = 0; ns < 4; ns++) {
        int n = nbase + ns * 16 + l15;
        int kind = n >> 9;
        int idx = n & 511;
        const float* bpb = kind == 0 ? bq : (kind == 1 ? bk : bv);
        biasv[ns] = bpb[idx];
    }

    #pragma unroll
    for (int ms = 0; ms < 4; ms++) {
        #pragma unroll
        for (int r = 0; r < 4; r++) {
            int m = mbase + ms * 16 + quad * 4 + r;
            int b = m / (TT * HWP);
            int rem = m - b * (TT * HWP);
            int t = rem / HWP;
            int p = rem - t * HWP;
            // V slot permutation (A-operand order within 32-key groups)
            int slot = ((p >> 5) << 5) + (((p >> 2) & 3) << 3) + (((p >> 4) & 1) << 2) + (p & 3);
            #pragma unroll
            for (int ns = 0; ns < 4; ns++) {
                int n = nbase + ns * 16 + l15;
                int kind = n >> 9;          // uniform across lanes
                int idx = n & 511;
                int head = idx >> 6;
                int ci = idx & 63;
                float val = acc[ms][ns][r] + biasv[ns];
                if (kind == 0) {
                    Qout[(((size_t)(b * NH + head) * TT + t) * HWP + p) * CID + ci]
                        = f2bf(val * LOG2E);
                } else if (kind == 1) {
                    Kout[(((size_t)(b * NH + head) * TP + (t + PPAD)) * HWP + p) * CID + ci]
                        = f2bf(val);
                } else {
                    Vtp[(((size_t)(b * NH + head) * TP + (t + PPAD)) * 64 + ci) * VSLOT + slot]
                        = f2bf(val);
                }
            }
        }
    }
}

// ---------------------------------------------------------------------------
// MFMA flash attention v2. One block = one wave = (b,n,t, quarter of 64 q).
// Per frame f (9): 7 aligned 32-key chunks (tail masked to 4 valid keys).
//   S^T via mfma(A=K,B=Q) -> D[key][q]; P = exp2(S') (Q pre-scaled log2e,
//   no max subtraction -- scores bounded); P packed (truncating v_perm) into
//   the PV A-frag directly; V read as contiguous dwordx4 from Vtp (global,
//   pre-permuted); l accumulated via mfma(P, ones) -> row-indexed like Y.
// No barriers in the loop. XCD swizzle keeps each (b,n) slab in one L2.
// Epilogue: LDS transpose -> coalesced z store + x residual.
// ---------------------------------------------------------------------------
__global__ __launch_bounds__(64) void attn_mfma2(
    const float* __restrict__ x,
    const u16* __restrict__ Qb, const u16* __restrict__ Kb,
    const u16* __restrict__ Vtp, float* __restrict__ zout)
{
    __shared__ float eT[64 * 67];

    int i = blockIdx.x;
    int xcd = i & 7;
    int r = i >> 3;
    int slab = ((r >> 7) << 3) | xcd;     // all 128 blocks of a slab on one XCD
    int inner = r & 127;
    int t = inner >> 2;
    int qr = inner & 3;
    int b = slab >> 3, n = slab & 7;

    int lane = threadIdx.x;
    int quad = lane >> 4, l15 = lane & 15;
    int q0 = qr * 64;

    const size_t krow0 = (size_t)slab * (TP * HWP);
    const u16* vslab = Vtp + (size_t)slab * (TP * 64 * VSLOT);
    const int vrow = l15 * VSLOT;

    // Persistent Q B-frags (Q pre-scaled by log2e at projection)
    short8 qf[4][2];
    #pragma unroll
    for (int tt = 0; tt < 4; tt++) {
        int qrow = q0 + tt * 16 + l15;
        qrow = qrow < HWP ? qrow : (HWP - 1);
        const u16* qp = Qb + ((size_t)(slab * TT + t) * HWP + qrow) * CID;
        qf[tt][0] = *(const short8*)(qp + quad * 8);
        qf[tt][1] = *(const short8*)(qp + 32 + quad * 8);
    }

    floatx4 acc[4][4];
    floatx4 accl[4];
    #pragma unroll
    for (int tt = 0; tt < 4; tt++) {
        #pragma unroll
        for (int cg = 0; cg < 4; cg++) acc[tt][cg] = (floatx4){0.f, 0.f, 0.f, 0.f};
        accl[tt] = (floatx4){0.f, 0.f, 0.f, 0.f};
    }

    union { u32 w[4]; short8 s; } ones;
    ones.w[0] = 0x3F803F80u; ones.w[1] = 0x3F803F80u;
    ones.w[2] = 0x3F803F80u; ones.w[3] = 0x3F803F80u;
    const floatx4 NEGBIG = (floatx4){-1e30f, -1e30f, -1e30f, -1e30f};

    for (int f = 0; f < KWIN; f++) {
        int rbase = (t + f) * HWP;
        const u16* vframe = vslab + (size_t)(t + f) * (64 * VSLOT) + vrow;

        for (int c = 0; c < 7; c++) {
            // K A-frags: 2 row-groups of 16 keys
            int row0 = rbase + c * 32 + l15;
            row0 = row0 < (TP * HWP) ? row0 : (TP * HWP - 1);
            const u16* kp0 = Kb + (krow0 + row0) * CID + quad * 8;
            short8 kf00 = *(const short8*)(kp0);
            short8 kf01 = *(const short8*)(kp0 + 32);
            short8 kf10, kf11;
            if (c < 6) {
                int row1 = rbase + c * 32 + 16 + l15;
                const u16* kp1 = Kb + (krow0 + row1) * CID + quad * 8;
                kf10 = *(const short8*)(kp1);
                kf11 = *(const short8*)(kp1 + 32);
            }
            // V B-frags: contiguous 16B from permuted layout
            const u16* vp = vframe + c * 32 + quad * 8;
            short8 vf0 = *(const short8*)(vp);
            short8 vf1 = *(const short8*)(vp + 16 * VSLOT);
            short8 vf2 = *(const short8*)(vp + 32 * VSLOT);
            short8 vf3 = *(const short8*)(vp + 48 * VSLOT);

            #pragma unroll
            for (int tt = 0; tt < 4; tt++) {
                floatx4 sc0 = (floatx4){0.f, 0.f, 0.f, 0.f};
                sc0 = __builtin_amdgcn_mfma_f32_16x16x32_bf16(kf00, qf[tt][0], sc0, 0, 0, 0);
                sc0 = __builtin_amdgcn_mfma_f32_16x16x32_bf16(kf01, qf[tt][1], sc0, 0, 0, 0);
                floatx4 sc1;
                if (c < 6) {
                    sc1 = (floatx4){0.f, 0.f, 0.f, 0.f};
                    sc1 = __builtin_amdgcn_mfma_f32_16x16x32_bf16(kf10, qf[tt][0], sc1, 0, 0, 0);
                    sc1 = __builtin_amdgcn_mfma_f32_16x16x32_bf16(kf11, qf[tt][1], sc1, 0, 0, 0);
                } else {
                    // tail: keys 192..195 valid only (quad 0 of group 0)
                    sc0 = (quad == 0) ? sc0 : NEGBIG;
                    sc1 = NEGBIG;
                }
                float e0 = exp2f(sc0[0]), e1 = exp2f(sc0[1]);
                float e2 = exp2f(sc0[2]), e3 = exp2f(sc0[3]);
                float e4 = exp2f(sc1[0]), e5 = exp2f(sc1[1]);
                float e6 = exp2f(sc1[2]), e7 = exp2f(sc1[3]);
                union { u32 w[4]; short8 s; } pf;
                pf.w[0] = packtrunc(e0, e1);
                pf.w[1] = packtrunc(e2, e3);
                pf.w[2] = packtrunc(e4, e5);
                pf.w[3] = packtrunc(e6, e7);

                acc[tt][0] = __builtin_amdgcn_mfma_f32_16x16x32_bf16(pf.s, vf0, acc[tt][0], 0, 0, 0);
                acc[tt][1] = __builtin_amdgcn_mfma_f32_16x16x32_bf16(pf.s, vf1, acc[tt][1], 0, 0, 0);
                acc[tt][2] = __builtin_amdgcn_mfma_f32_16x16x32_bf16(pf.s, vf2, acc[tt][2], 0, 0, 0);
                acc[tt][3] = __builtin_amdgcn_mfma_f32_16x16x32_bf16(pf.s, vf3, acc[tt][3], 0, 0, 0);
                accl[tt]   = __builtin_amdgcn_mfma_f32_16x16x32_bf16(pf.s, ones.s, accl[tt], 0, 0, 0);
            }
        }
    }

    // Normalize and transpose through LDS for coalesced stores.
    #pragma unroll
    for (int tt = 0; tt < 4; tt++) {
        float il[4];
        #pragma unroll
        for (int rr = 0; rr < 4; rr++) il[rr] = 1.0f / accl[tt][rr];
        #pragma unroll
        for (int cg = 0; cg < 4; cg++)
            #pragma unroll
            for (int rr = 0; rr < 4; rr++)
                eT[(tt * 16 + quad * 4 + rr) * 67 + cg * 16 + l15] = acc[tt][cg][rr] * il[rr];
    }
    __syncthreads();

    int p = q0 + lane;
    bool ok = p < HWP;
    size_t base = ((size_t)(b * CC + n * CID) * TT + t) * HWP + p;
    for (int ci = 0; ci < 64; ci++) {
        if (ok) {
            size_t a = base + (size_t)ci * (TT * HWP);
            zout[a] = eT[lane * 67 + ci] + x[a];
        }
    }
}

// ---------------------------------------------------------------------------
extern "C" void kernel_launch(void* const* d_in, const int* in_sizes, int n_in,
                              void* d_out, int out_size, void* d_ws, size_t ws_size,
                              hipStream_t stream) {
    const float* x  = (const float*)d_in[0];
    const float* Wq = (const float*)d_in[1];
    const float* bq = (const float*)d_in[2];
    const float* Wk = (const float*)d_in[3];
    const float* bk = (const float*)d_in[4];
    const float* Wv = (const float*)d_in[5];
    const float* bv = (const float*)d_in[6];
    float* z = (float*)d_out;

    // Workspace (bf16): Q [16][T][HW][CI], K [16][Tp][HW][CI],
    //                   Vtp [16][Tp][CI][224], W [1536][512]  (~48.8 MB)
    // xt [(b,t,p)][c] lives in d_out (dead until attn writes z).
    const size_t qElems   = (size_t)BB * NH * TT * HWP * CID;   // 6,422,528
    const size_t kElems   = (size_t)BB * NH * TP * HWP * CID;   // 8,028,160
    const size_t vtpElems = (size_t)BB * NH * TP * 64 * VSLOT;  // 9,175,040

    u16* Qw  = (u16*)d_ws;
    u16* Kw  = Qw + qElems;
    u16* Vtp = Kw + kElems;
    u16* Wb  = Vtp + vtpElems;
    u16* Xt  = (u16*)d_out;

    convert_w<<<(NTOT * CC / 2 + 255) / 256, 256, 0, stream>>>(Wq, Wk, Wv, Wb);
    transpose_x<<<BB * TT * 8, 256, 0, stream>>>(x, Xt);
    {
        const int kper = 2 * NH * 8 * HWP * 32;
        const int vper = 2 * NH * 8 * 64 * (VSLOT / 2);
        pad_fill<<<(kper + vper + 255) / 256, 256, 0, stream>>>(bk, bv, Kw, Vtp);
    }
    proj_gemm<<<(MTOT / 64) * 6, 256, 0, stream>>>(Xt, Wb, bq, bk, bv, Qw, Kw, Vtp);
    // 16 slabs * 32 t * 4 quarters, XCD-swizzled, one wave per block
    attn_mfma2<<<2048, 64, 0, stream>>>(x, Qw, Kw, Vtp, z);
}